// Round 3
// baseline (174.411 us; speedup 1.0000x reference)
//
#include <hip/hip_runtime.h>
#include <stdint.h>

// Problem constants
#define B_   16
#define D_   256
#define T_   4096
#define K_   1024
#define N_   (B_ * T_)      // 65536 points
#define BM   64             // points per block

typedef __attribute__((ext_vector_type(4))) float floatx4;
typedef __attribute__((ext_vector_type(2))) float floatx2;
typedef __attribute__((ext_vector_type(2))) long longx2;

// ---- Kernel 0: emb fp32 -> fp8 e4m3 (scaled x1024), stored in B-FRAGMENT order:
//      byte for (row c, d) at c*256 + quad*64 + kk*8 + (d&7), kk=d>>5, quad=(d>>3)&3
//      -> lane (ml,quad) reads its 2 consecutive k-frags as one dwordx4.
//      esqh[c] = 1024 * 0.5 * ||e_exact||^2 (pre-quantization norms). Also zeroes loss.
__global__ __launch_bounds__(256) void emb_prep(const float* __restrict__ emb,
                                                uint32_t* __restrict__ embf8,
                                                float* __restrict__ esqh,
                                                float* __restrict__ lossp) {
    int w = threadIdx.x >> 6, lane = threadIdx.x & 63;
    int k = blockIdx.x * 4 + w;                       // one wave per code row
    float4 v = ((const float4*)emb)[k * 64 + lane];   // d0 = lane*4
    float a0 = v.x * 1024.f, a1 = v.y * 1024.f, a2 = v.z * 1024.f, a3 = v.w * 1024.f;
    int p = __builtin_amdgcn_cvt_pk_fp8_f32(a0, a1, 0, false);
    p = __builtin_amdgcn_cvt_pk_fp8_f32(a2, a3, p, true);
    // word index in frag order: quad*16 + kk*2 + (d0&4)/4 ; d0 = lane*4
    int widx = ((lane >> 1) & 3) * 16 + (lane >> 3) * 2 + (lane & 1);
    embf8[k * 64 + widx] = (uint32_t)p;
    float ss = a0 * a0 + a1 * a1 + a2 * a2 + a3 * a3;   // exact (pre-fp8) scaled norm
    #pragma unroll
    for (int off = 32; off; off >>= 1) ss += __shfl_xor(ss, off, 64);
    if (lane == 0) esqh[k] = ss * (0.5f / 1024.f);      // = 1024 * 0.5*||e||^2
    if (blockIdx.x == 0 && threadIdx.x == 0) *lossp = 0.f;
}

// ---- Main kernel ----
// xs swizzle (phases 1-3), byte offset of d in row t:
//   c=d>>4, h=(d>>3)&1 -> ((c ^ (t&15))<<4) + ((h ^ ((t>>4)&1))<<3) + (d&7)
// Phase 4 reuses xs with a 16B-chunk swizzle: chunk g at ((g ^ (t&15))<<4).
// Work split: wave w -> point-half ph=w&1 (2 MFMA A-sets), code-half ch=w>>1
// (32 tiles of 16 codes streamed straight from L2). K-loop has NO barriers.
__global__ __launch_bounds__(256, 4) void vq_main(const float* __restrict__ z,
                                                  const uint32_t* __restrict__ embf8,
                                                  const float* __restrict__ esqh,
                                                  float* __restrict__ out0,
                                                  float* __restrict__ lossp) {
    __shared__ __align__(16) unsigned char xs[BM * 256];   // 16 KiB
    __shared__ float wvals[2][BM];
    __shared__ int   widx[2][BM];
    __shared__ int   pidx[BM];
    __shared__ float zred[4];

    int tid  = threadIdx.x;
    int lane = tid & 63, w = tid >> 6;
    int ml   = lane & 15, quad = lane >> 4;
    int ph   = w & 1, ch = w >> 1;
    int blk  = blockIdx.x;
    int b    = blk >> 6;
    int t0   = (blk & 63) * BM;
    const float* zb = z + (size_t)b * (D_ * T_) + t0;

    // ---- Phase 1: load z [d][t], fp8-convert, transposed+swizzled store; Sum z^2 ----
    float zsq = 0.f;
    {
        int t = lane, hf = (t >> 4) & 1;
        #pragma unroll 2
        for (int j = 0; j < 8; ++j) {
            int dgrp = w + 4 * j;
            int d0 = dgrp * 8;
            float f0 = zb[(d0 + 0) * T_ + t];
            float f1 = zb[(d0 + 1) * T_ + t];
            float f2 = zb[(d0 + 2) * T_ + t];
            float f3 = zb[(d0 + 3) * T_ + t];
            float f4 = zb[(d0 + 4) * T_ + t];
            float f5 = zb[(d0 + 5) * T_ + t];
            float f6 = zb[(d0 + 6) * T_ + t];
            float f7 = zb[(d0 + 7) * T_ + t];
            zsq += f0*f0 + f1*f1 + f2*f2 + f3*f3 + f4*f4 + f5*f5 + f6*f6 + f7*f7;
            uint32_t p0 = (uint32_t)__builtin_amdgcn_cvt_pk_fp8_f32(f0, f1, 0, false);
            p0 = (uint32_t)__builtin_amdgcn_cvt_pk_fp8_f32(f2, f3, (int)p0, true);
            uint32_t p1 = (uint32_t)__builtin_amdgcn_cvt_pk_fp8_f32(f4, f5, 0, false);
            p1 = (uint32_t)__builtin_amdgcn_cvt_pk_fp8_f32(f6, f7, (int)p1, true);
            int c = dgrp >> 1, h = dgrp & 1;
            *(uint2*)&xs[t * 256 + ((c ^ (t & 15)) << 4) + ((h ^ hf) << 3)] =
                make_uint2(p0, p1);
        }
    }
    __syncthreads();

    // ---- Phase 2: persistent A fragments, 2 point-sets per wave ----
    long afr[2][8];
    #pragma unroll
    for (int s = 0; s < 2; ++s) {
        int p = (ph * 2 + s) * 16 + ml;     // (p>>4)&1 == s
        #pragma unroll
        for (int kk = 0; kk < 8; ++kk) {
            int c = 2 * kk + (quad >> 1), h = quad & 1;
            afr[s][kk] = *(const long*)&xs[p * 256 + ((c ^ ml) << 4) + ((h ^ s) << 3)];
        }
    }

    float bv[2][4]; int bi[2][4];
    #pragma unroll
    for (int s = 0; s < 2; ++s)
        #pragma unroll
        for (int i = 0; i < 4; ++i) { bv[s][i] = 1e30f; bi[s][i] = 0; }

    // ---- Phase 3: barrier-free k-loop, B-frags streamed from L2 ----
    const char* eb = (const char*)embf8;
    #pragma unroll 2
    for (int j = 0; j < 32; ++j) {
        int kt = ch * 32 + j;
        int c  = kt * 16 + ml;
        const longx2* brow = (const longx2*)(eb + (size_t)c * 256 + quad * 64);
        longx2 q0 = brow[0], q1 = brow[1], q2 = brow[2], q3 = brow[3];
        float eh = esqh[c];
        floatx4 acc0 = {0.f, 0.f, 0.f, 0.f};
        floatx4 acc1 = {0.f, 0.f, 0.f, 0.f};
        long bf[8] = {q0[0], q0[1], q1[0], q1[1], q2[0], q2[1], q3[0], q3[1]};
        #pragma unroll
        for (int kk = 0; kk < 8; ++kk) {
            acc0 = __builtin_amdgcn_mfma_f32_16x16x32_fp8_fp8(afr[0][kk], bf[kk], acc0, 0, 0, 0);
            acc1 = __builtin_amdgcn_mfma_f32_16x16x32_fp8_fp8(afr[1][kk], bf[kk], acc1, 0, 0, 0);
        }
        #pragma unroll
        for (int i = 0; i < 4; ++i) {
            float v0 = eh - acc0[i];
            if (v0 < bv[0][i]) { bv[0][i] = v0; bi[0][i] = c; }
            float v1 = eh - acc1[i];
            if (v1 < bv[1][i]) { bv[1][i] = v1; bi[1][i] = c; }
        }
    }

    // ---- per-wave argmin over the 16 code-lanes; publish candidates ----
    #pragma unroll
    for (int s = 0; s < 2; ++s)
        #pragma unroll
        for (int i = 0; i < 4; ++i) {
            float v = bv[s][i]; int ii = bi[s][i];
            #pragma unroll
            for (int off = 1; off < 16; off <<= 1) {
                float ov = __shfl_xor(v, off, 64);
                int   oi = __shfl_xor(ii, off, 64);
                if (ov < v || (ov == v && oi < ii)) { v = ov; ii = oi; }
            }
            if (ml == 0) {
                int pt = (ph * 2 + s) * 16 + quad * 4 + i;
                wvals[ch][pt] = v; widx[ch][pt] = ii;
            }
        }
    #pragma unroll
    for (int off = 32; off; off >>= 1) zsq += __shfl_xor(zsq, off, 64);
    if (lane == 0) zred[w] = zsq;
    __syncthreads();

    // ---- cross-wave merge (wave 0) + loss via algebra ----
    if (tid < 64) {
        int t = tid;
        float v0 = wvals[0][t]; int i0 = widx[0][t];
        float v1 = wvals[1][t]; int i1 = widx[1][t];
        float wv = v0; int wi = i0;
        if (v1 < v0 || (v1 == v0 && i1 < i0)) { wv = v1; wi = i1; }
        pidx[t] = wi;
        float lsum = wv;          // winning bv = 1024*(0.5||e||^2 - x.e)
        #pragma unroll
        for (int off = 32; off; off >>= 1) lsum += __shfl_xor(lsum, off, 64);
        if (t == 0) {
            float tot = zred[0] + zred[1] + zred[2] + zred[3] + lsum * (2.0f / 1024.f);
            atomicAdd(lossp, tot * (1.25f / 16777216.0f));   // 1.25/(N*D)
        }
    }
    __syncthreads();

    // ---- Phase 4a: gather winning fp8 rows into xs (coalesced) ----
    #pragma unroll
    for (int m = 0; m < 4; ++m) {
        int t   = (tid >> 4) + 16 * m;
        int off = tid & 15;
        int code = pidx[t];
        uint4 v = ((const uint4*)embf8)[code * 16 + off];
        *(uint4*)&xs[t * 256 + ((off ^ (t & 15)) << 4)] = v;
    }
    __syncthreads();

    // ---- Phase 4b: dequant + transpose-write (frag-order byte decode) ----
    float* ob = out0 + (size_t)b * (D_ * T_) + t0;
    {
        int t = lane;
        #pragma unroll
        for (int j = 0; j < 4; ++j) {
            int g = w + 4 * j;            // 16-byte chunk 0..15
            uint4 v = *(const uint4*)&xs[t * 256 + ((g ^ (t & 15)) << 4)];
            uint32_t wd[4] = {v.x, v.y, v.z, v.w};
            #pragma unroll
            for (int u = 0; u < 4; ++u) {
                int kk = (g & 3) * 2 + (u >> 1);
                int d0 = kk * 32 + (g >> 2) * 8 + (u & 1) * 4;
                floatx2 lo = __builtin_amdgcn_cvt_pk_f32_fp8((int)wd[u], false);
                floatx2 hi = __builtin_amdgcn_cvt_pk_f32_fp8((int)wd[u], true);
                ob[(d0 + 0) * T_ + t] = lo[0] * (1.f / 1024.f);
                ob[(d0 + 1) * T_ + t] = lo[1] * (1.f / 1024.f);
                ob[(d0 + 2) * T_ + t] = hi[0] * (1.f / 1024.f);
                ob[(d0 + 3) * T_ + t] = hi[1] * (1.f / 1024.f);
            }
        }
    }
}

extern "C" void kernel_launch(void* const* d_in, const int* in_sizes, int n_in,
                              void* d_out, int out_size, void* d_ws, size_t ws_size,
                              hipStream_t stream) {
    (void)in_sizes; (void)n_in; (void)out_size; (void)ws_size;
    const float* z   = (const float*)d_in[0];
    const float* emb = (const float*)d_in[1];

    uint32_t* embf8 = (uint32_t*)d_ws;                              // 256 KiB
    float*    esqh  = (float*)((char*)d_ws + (size_t)K_ * D_);      // 4 KiB

    float* out0  = (float*)d_out;
    float* lossp = out0 + (size_t)N_ * D_;

    emb_prep<<<K_ / 4, 256, 0, stream>>>(emb, embf8, esqh, lossp);
    vq_main<<<N_ / BM, 256, 0, stream>>>(z, embf8, esqh, out0, lossp);
}